// Round 7
// baseline (5825.260 us; speedup 1.0000x reference)
//
#include <hip/hip_runtime.h>
#include <cstdint>
#include <cstddef>

// SO3NeuralCDE: B=16384, S=64, C=9, H=128, BN=64.
// RK4 over 63 knot intervals; field = 4-layer MLP (elu,elu,elu,tanh) contracted with dX.
// dt cancels: K_i = f(.) * (x[k+1]-x[k]).  t input unused.
//
// Precision: split fp16 (X = Xh + Xl) on every GEMM input; each logical MFMA =
// 3 MFMAs (Ah*Bh + Al*Bh + Ah*Bl), fp32 accumulate -> ~fp32-precision GEMMs.
//
// Round-6 lesson: MFMA pipe starved at 2 lockstep waves/SIMD (1 block/CU,
// LDS-bound by the 64KB W123 copy). Round 7: 32-row tiles, 512 blocks, ~38KB
// LDS -> 2 independent blocks/CU (4 waves/SIMD, decoupled barriers). W123
// fragments stream from L2 per stage (transient regs, 1-GEMM-ahead prefetch).
// VGPR <=128 enforced by __launch_bounds__(512,4).

typedef _Float16 f16;
typedef _Float16 f16x8 __attribute__((ext_vector_type(8)));
typedef float f32x4 __attribute__((ext_vector_type(4)));

#define LOG2E     1.44269504088896340736f
#define TWOLOG2E  2.88539008177792681472f

#define MFMA3(acc, ah, al, bh, bl)                                        \
  acc = __builtin_amdgcn_mfma_f32_16x16x32_f16(ah, bh, acc, 0, 0, 0);     \
  acc = __builtin_amdgcn_mfma_f32_16x16x32_f16(al, bh, acc, 0, 0, 0);     \
  acc = __builtin_amdgcn_mfma_f32_16x16x32_f16(ah, bl, acc, 0, 0, 0);

// ws layout in f16 elements (hi at [0,90112), lo at [90112,180224)):
//   [0,8192)      W1P  (K=128,N=64)   frag idx ((nt*4+kb)*64+l)*8+j
//   [8192,12288)  W2P  (K=64,N=64)    ((nt*2+kb)*64+l)*8+j
//   [12288,16384) W3P  (K=64,N=64)
//   [16384,90112) W4P  per c: (K=64,N=128 cols 9h+c)  (((c*8+nt)*2+kb)*64+l)*8+j
__global__ void pack_weights(const float* __restrict__ W1, const float* __restrict__ W2,
                             const float* __restrict__ W3, const float* __restrict__ W4,
                             f16* __restrict__ wp)
{
  int t = blockIdx.x * 256 + threadIdx.x;
  if (t >= 90112) return;
  float v;
  if (t < 8192) {
    int j = t & 7, lr = (t >> 3) & 63, kb = (t >> 9) & 3, nt = t >> 11;
    int k = 32*kb + 8*(lr >> 4) + j, n = 16*nt + (lr & 15);
    v = W1[k*64 + n];
  } else if (t < 12288) {
    int u = t - 8192;
    int j = u & 7, lr = (u >> 3) & 63, kb = (u >> 9) & 1, nt = u >> 10;
    int k = 32*kb + 8*(lr >> 4) + j, n = 16*nt + (lr & 15);
    v = W2[k*64 + n];
  } else if (t < 16384) {
    int u = t - 12288;
    int j = u & 7, lr = (u >> 3) & 63, kb = (u >> 9) & 1, nt = u >> 10;
    int k = 32*kb + 8*(lr >> 4) + j, n = 16*nt + (lr & 15);
    v = W3[k*64 + n];
  } else {
    int u = t - 16384;
    int j = u & 7, lr = (u >> 3) & 63, kb = (u >> 9) & 1, nt = (u >> 10) & 7, c = u >> 13;
    int k = 32*kb + 8*(lr >> 4) + j, h = 16*nt + (lr & 15);
    v = W4[k*1152 + 9*h + c];
  }
  f16 hi = (f16)v;
  wp[t] = hi;
  wp[90112 + t] = (f16)(v - (float)hi);
}

__device__ __forceinline__ void tanh_k4(f32x4& K, const f32x4 ac, float b4c, const f32x4 uv) {
#pragma unroll
  for (int r = 0; r < 4; r++) {
    // tanh(pre + b4) = 1 - 2/(exp2((pre+b4)*2log2e)+1)  (inf-safe); b4c pre-scaled
    float tex = __builtin_amdgcn_exp2f(__builtin_fmaf(ac[r], TWOLOG2E, b4c));
    float th  = __builtin_fmaf(__builtin_amdgcn_rcpf(tex + 1.0f), -2.0f, 1.0f);
    K[r] = __builtin_fmaf(th, uv[r], K[r]);
  }
}

// W4 fragment set for channel c, this wave's 16 cols (nt=w): 4 x f16x8 = 16 VGPRs.
#define LOADSET(P, c) do {                                                \
    int base_ = 2048 + (((c)*8 + w)*2)*64 + l;                            \
    P##h0 = wpv[base_];      P##l0 = wlv[base_];                          \
    P##h1 = wpv[base_ + 64]; P##l1 = wlv[base_ + 64];                     \
  } while (0)

// Compute channel c with set P: 4 logical MFMAs (x3 split), tanh, K4 fma.
#define COMPUTE(P, c) do {                                                \
    f32x4 ac0 = zero4, ac1 = zero4;                                       \
    MFMA3(ac0, a4h[0][0], a4l[0][0], P##h0, P##l0);                       \
    MFMA3(ac0, a4h[0][1], a4l[0][1], P##h1, P##l1);                       \
    MFMA3(ac1, a4h[1][0], a4l[1][0], P##h0, P##l0);                       \
    MFMA3(ac1, a4h[1][1], a4l[1][1], P##h1, P##l1);                       \
    float b4c = ((const float*)(smem + B4S))[(c)*128 + colG4];            \
    f32x4 uv0 = *reinterpret_cast<const f32x4*>(smem + UT + (c)*128 + 16*l4);      \
    f32x4 uv1 = *reinterpret_cast<const f32x4*>(smem + UT + (c)*128 + 64 + 16*l4); \
    tanh_k4(K4[0], ac0, b4c, uv0);                                        \
    tanh_k4(K4[1], ac1, b4c, uv1);                                        \
  } while (0)

// LDS map (38528 B), 32-row tile:
//   s_hi[32][128]f16 @0     (8K, rowstride 256B, XOR-swizzled)   s_lo @8192
//   hA_hi[32][64]f16 @16384 (4K, rowstride 128B, swizzled)       hA_lo @20480
//   hB_hi @24576                                                  hB_lo @28672
//   u_t[9][32]f32 @32768 (1152 B)
//   b4s[9][128]f32 @33920 (4608 B)  b4s[c*128+h] = b4[9h+c]*2log2e
// G1: s->hA; G2: hA->hB; G3: hB->hA; G4: hA.  W1-4 stream from global/L2.
// 8 waves: G1-3 (mh=w>>2 16-row half, nq=w&3 16-col quarter), one tile each;
//          G4/state: rows 0..31 (2 mi), cols colG4=16w+l15.
__global__ __launch_bounds__(512, 4) void cde_main(
    const float* __restrict__ x, const f16* __restrict__ wp,
    const float* __restrict__ b1, const float* __restrict__ b2,
    const float* __restrict__ b3, const float* __restrict__ b4,
    const float* __restrict__ Wi, const float* __restrict__ bi,
    const float* __restrict__ Wo, const float* __restrict__ bo,
    float* __restrict__ out)
{
  constexpr int SH = 0, SL = 8192, HAH = 16384, HAL = 20480, HBH = 24576, HBL = 28672;
  constexpr int UT = 32768, B4S = 33920;
  __shared__ __attribute__((aligned(16))) char smem[38528];

  const int tid = threadIdx.x;
  const int w   = tid >> 6;          // wave 0..7
  const int l   = tid & 63;
  const int l15 = l & 15, l4 = l >> 4;
  const int mh  = w >> 2, nq = w & 3;        // G1-G3 roles
  const int b0  = blockIdx.x << 5;           // batch tile base (32 rows)
  const int colG4 = (w << 4) + l15;          // G4/state column
  const int xorv  = (l15 & 7) << 4;          // A-frag read swizzle (row = ..+l15)

  const f16x8* wpv = reinterpret_cast<const f16x8*>(wp);
  const f16x8* wlv = wpv + 11264;            // lo half (90112/8)

  const float b1v = b1[(nq<<4) + l15], b2v = b2[(nq<<4) + l15], b3v = b3[(nq<<4) + l15];
  const float b1x = b1v * LOG2E, b2x = b2v * LOG2E, b3x = b3v * LOG2E;

  const f32x4 zero4 = {0.f, 0.f, 0.f, 0.f};

  // ---------------- init LDS: b4s, Wi (@HAH), bi (@HBH), x0 (@UT) ----------------
  for (int idx = tid; idx < 1152; idx += 512) {
    int h = idx / 9, c = idx - h*9;                     // coalesced read of b4
    ((float*)(smem + B4S))[c*128 + h] = b4[idx] * TWOLOG2E;
  }
  for (int idx = tid; idx < 1152; idx += 512) ((float*)(smem + HAH))[idx] = Wi[idx];
  if (tid < 128) ((float*)(smem + HBH))[tid] = bi[tid];
  if (tid < 288) {
    int row = tid / 9, c = tid - row*9;                 // coalesced read of x0
    ((float*)(smem + UT))[c*32 + row] = x[(size_t)(b0 + row)*576 + c];
  }
  __syncthreads();

  // RK4 state: rows 16mi+4l4+r (mi 0..1), col colG4
  f32x4 z[2], ark[2], K4[2];
  {
    float wiv[9];
#pragma unroll
    for (int c = 0; c < 9; c++) wiv[c] = ((const float*)(smem + HAH))[c*128 + colG4];
    float biv = ((const float*)(smem + HBH))[colG4];
#pragma unroll
    for (int mi = 0; mi < 2; mi++) {
      f32x4 zz = {biv, biv, biv, biv};
#pragma unroll
      for (int c = 0; c < 9; c++) {
        f32x4 xv = *reinterpret_cast<const f32x4*>(smem + UT + c*128 + 64*mi + 16*l4);
#pragma unroll
        for (int r = 0; r < 4; r++) zz[r] = __builtin_fmaf(xv[r], wiv[c], zz[r]);
      }
      z[mi] = zz;
#pragma unroll
      for (int r = 0; r < 4; r++) {           // seed s with z0 (split hi/lo)
        int row  = 16*mi + 4*l4 + r;
        int byte = row*256 + ((colG4*2) ^ ((row & 7) << 4));
        f16 hi = (f16)zz[r];
        *reinterpret_cast<f16*>(smem + SH + byte) = hi;
        *reinterpret_cast<f16*>(smem + SL + byte) = (f16)(zz[r] - (float)hi);
      }
    }
  }

  // ---------------- time loop ----------------
#pragma unroll 1
  for (int k = 0; k < 63; ++k) {
#pragma unroll 1
    for (int st = 0; st < 4; ++st) {
      __syncthreads();                         // s (and prior u_t use) settled

      // W1 fragments for this wave's nq slice (global/L2, transient)
      f16x8 w1h[4], w1l[4];
#pragma unroll
      for (int kb = 0; kb < 4; kb++) {
        int i = (nq*4 + kb)*64 + l;
        w1h[kb] = wpv[i]; w1l[kb] = wlv[i];
      }

      if (st == 0 && tid < 288) {              // u_t[c][row] = x[k+1]-x[k], coalesced
        int row = tid / 9, c = tid - row*9;
        const float* p = x + (size_t)(b0 + row)*576 + (size_t)k*9 + c;
        ((float*)(smem + UT))[c*32 + row] = p[9] - p[0];
      }

      f16x8 w2h[2], w2l[2], w3h[2], w3l[2];
      f16x8 Ah0, Al0, Ah1, Al1, Bh0, Bl0, Bh1, Bl1;

      // ---- G1: s(32x128) @ W1 -> h1 (hA); one 16x16 tile/wave ----
      {
        f32x4 acc = zero4;
#pragma unroll
        for (int kb = 0; kb < 4; kb++) {
          int row = 16*mh + l15;
          int off = row*256 + ((16*l4 + 64*kb) ^ xorv);
          f16x8 ah = *reinterpret_cast<const f16x8*>(smem + SH + off);
          f16x8 al = *reinterpret_cast<const f16x8*>(smem + SL + off);
          MFMA3(acc, ah, al, w1h[kb], w1l[kb]);
        }
#pragma unroll
        for (int kb = 0; kb < 2; kb++) {       // prefetch W2
          int i = 1024 + (nq*2 + kb)*64 + l;
          w2h[kb] = wpv[i]; w2l[kb] = wlv[i];
        }
#pragma unroll
        for (int r = 0; r < 4; r++) {
          float pre = acc[r];
          float lin = pre + b1v;
          float e   = __builtin_amdgcn_exp2f(__builtin_fmaf(pre, LOG2E, b1x)) - 1.0f;
          float res = lin > 0.0f ? lin : e;
          int row  = 16*mh + 4*l4 + r;
          int byte = row*128 + ((((nq<<4) + l15)*2) ^ ((row & 7) << 4));
          f16 hi = (f16)res;
          *reinterpret_cast<f16*>(smem + HAH + byte) = hi;
          *reinterpret_cast<f16*>(smem + HAL + byte) = (f16)(res - (float)hi);
        }
      }
      __syncthreads();

      // ---- G2: h1(hA) @ W2 -> h2 (hB) ----
      {
        f32x4 acc = zero4;
#pragma unroll
        for (int kb = 0; kb < 2; kb++) {
          int row = 16*mh + l15;
          int off = row*128 + ((16*l4 + 64*kb) ^ xorv);
          f16x8 ah = *reinterpret_cast<const f16x8*>(smem + HAH + off);
          f16x8 al = *reinterpret_cast<const f16x8*>(smem + HAL + off);
          MFMA3(acc, ah, al, w2h[kb], w2l[kb]);
        }
#pragma unroll
        for (int kb = 0; kb < 2; kb++) {       // prefetch W3
          int i = 1536 + (nq*2 + kb)*64 + l;
          w3h[kb] = wpv[i]; w3l[kb] = wlv[i];
        }
#pragma unroll
        for (int r = 0; r < 4; r++) {
          float pre = acc[r];
          float lin = pre + b2v;
          float e   = __builtin_amdgcn_exp2f(__builtin_fmaf(pre, LOG2E, b2x)) - 1.0f;
          float res = lin > 0.0f ? lin : e;
          int row  = 16*mh + 4*l4 + r;
          int byte = row*128 + ((((nq<<4) + l15)*2) ^ ((row & 7) << 4));
          f16 hi = (f16)res;
          *reinterpret_cast<f16*>(smem + HBH + byte) = hi;
          *reinterpret_cast<f16*>(smem + HBL + byte) = (f16)(res - (float)hi);
        }
      }
      __syncthreads();

      // ---- G3: h2(hB) @ W3 -> h3 (hA, reuse) ----
      {
        f32x4 acc = zero4;
#pragma unroll
        for (int kb = 0; kb < 2; kb++) {
          int row = 16*mh + l15;
          int off = row*128 + ((16*l4 + 64*kb) ^ xorv);
          f16x8 ah = *reinterpret_cast<const f16x8*>(smem + HBH + off);
          f16x8 al = *reinterpret_cast<const f16x8*>(smem + HBL + off);
          MFMA3(acc, ah, al, w3h[kb], w3l[kb]);
        }
        LOADSET(A, 0);                         // prefetch W4 c=0
#pragma unroll
        for (int r = 0; r < 4; r++) {
          float pre = acc[r];
          float lin = pre + b3v;
          float e   = __builtin_amdgcn_exp2f(__builtin_fmaf(pre, LOG2E, b3x)) - 1.0f;
          float res = lin > 0.0f ? lin : e;
          int row  = 16*mh + 4*l4 + r;
          int byte = row*128 + ((((nq<<4) + l15)*2) ^ ((row & 7) << 4));
          f16 hi = (f16)res;
          *reinterpret_cast<f16*>(smem + HAH + byte) = hi;
          *reinterpret_cast<f16*>(smem + HAL + byte) = (f16)(res - (float)hi);
        }
      }
      __syncthreads();

      // ---- G4: 9 channel-GEMMs (h3 @ W4_c), tanh, contract with u, RK4 ----
      // rows 0..31 (2 mi), cols colG4; paired-c named A/B prefetch sets.
      {
        f16x8 a4h[2][2], a4l[2][2];
#pragma unroll
        for (int mi = 0; mi < 2; mi++)
#pragma unroll
          for (int kb = 0; kb < 2; kb++) {
            int row = 16*mi + l15;
            int off = row*128 + ((16*l4 + 64*kb) ^ xorv);
            a4h[mi][kb] = *reinterpret_cast<const f16x8*>(smem + HAH + off);
            a4l[mi][kb] = *reinterpret_cast<const f16x8*>(smem + HAL + off);
          }
        K4[0] = zero4; K4[1] = zero4;

        LOADSET(B, 1);
#pragma unroll 1
        for (int cc = 0; cc < 4; ++cc) {       // channels (2cc, 2cc+1), prefetch +2
          COMPUTE(A, 2*cc);
          LOADSET(A, 2*cc + 2);                // c = 2,4,6,8
          COMPUTE(B, 2*cc + 1);
          if (cc < 3) LOADSET(B, 2*cc + 3);    // c = 3,5,7
        }
        COMPUTE(A, 8);

        // RK4 combine (K = h*k): ark=K1+2K2+2K3; z += (ark+K4)/6
        if (st == 0) {
#pragma unroll
          for (int mi = 0; mi < 2; mi++) ark[mi] = K4[mi];
        } else if (st == 3) {
#pragma unroll
          for (int mi = 0; mi < 2; mi++)
#pragma unroll
            for (int r = 0; r < 4; r++)
              z[mi][r] = __builtin_fmaf(ark[mi][r] + K4[mi][r], 0.166666666667f, z[mi][r]);
        } else {
#pragma unroll
          for (int mi = 0; mi < 2; mi++)
#pragma unroll
            for (int r = 0; r < 4; r++)
              ark[mi][r] = __builtin_fmaf(2.0f, K4[mi][r], ark[mi][r]);
        }
        const float alpha = (st == 2) ? 1.0f : 0.5f;
#pragma unroll
        for (int mi = 0; mi < 2; mi++)
#pragma unroll
          for (int r = 0; r < 4; r++) {
            float sv = (st == 3) ? z[mi][r] : __builtin_fmaf(alpha, K4[mi][r], z[mi][r]);
            int row  = 16*mi + 4*l4 + r;
            int byte = row*256 + ((colG4*2) ^ ((row & 7) << 4));
            f16 hi = (f16)sv;
            *reinterpret_cast<f16*>(smem + SH + byte) = hi;
            *reinterpret_cast<f16*>(smem + SL + byte) = (f16)(sv - (float)hi);
          }
      }
    }
  }

  // ---------------- out = z @ Wo + bo ----------------
  __syncthreads();
#pragma unroll
  for (int mi = 0; mi < 2; mi++)
#pragma unroll
    for (int r = 0; r < 4; r++) {
      int row = 16*mi + 4*l4 + r;
      ((float*)smem)[row*128 + colG4] = z[mi][r];        // z32[32][128] @0 (16 KB)
    }
  for (int idx = tid; idx < 1152; idx += 512) ((float*)(smem + HAH))[idx] = Wo[idx];
  __syncthreads();
  if (tid < 288) {
    int b_ = tid / 9, c = tid - b_*9;
    float acc = bo[c];
#pragma unroll 4
    for (int h = 0; h < 128; h++)
      acc = __builtin_fmaf(((const float*)smem)[b_*128 + h],
                           ((const float*)(smem + HAH))[h*9 + c], acc);
    out[(size_t)(b0 + b_)*9 + c] = acc;
  }
}

extern "C" void kernel_launch(void* const* d_in, const int* in_sizes, int n_in,
                              void* d_out, int out_size, void* d_ws, size_t ws_size,
                              hipStream_t stream)
{
  // setup_inputs order: t, x, W1, b1, W2, b2, W3, b3, W4, b4, Wi, bi, Wo, bo
  const float* x  = (const float*)d_in[1];
  const float* W1 = (const float*)d_in[2];
  const float* b1 = (const float*)d_in[3];
  const float* W2 = (const float*)d_in[4];
  const float* b2 = (const float*)d_in[5];
  const float* W3 = (const float*)d_in[6];
  const float* b3 = (const float*)d_in[7];
  const float* W4 = (const float*)d_in[8];
  const float* b4 = (const float*)d_in[9];
  const float* Wi = (const float*)d_in[10];
  const float* bi = (const float*)d_in[11];
  const float* Wo = (const float*)d_in[12];
  const float* bo = (const float*)d_in[13];
  f16* wp = (f16*)d_ws;                       // 180224 f16 = 360448 B (hi + lo)

  pack_weights<<<352, 256, 0, stream>>>(W1, W2, W3, W4, wp);
  cde_main<<<512, 512, 0, stream>>>(x, wp, b1, b2, b3, b4, Wi, bi, Wo, bo, (float*)d_out);
}

// Round 8
// 4638.381 us; speedup vs baseline: 1.2559x; 1.2559x over previous
//
#include <hip/hip_runtime.h>
#include <cstdint>
#include <cstddef>

// SO3NeuralCDE: B=16384, S=64, C=9, H=128, BN=64.
// RK4 over 63 knot intervals; field = 4-layer MLP (elu,elu,elu,tanh) contracted with dX.
// dt cancels: K_i = f(.) * (x[k+1]-x[k]).  t input unused.
//
// Precision: split fp16 (X = Xh + Xl) on every GEMM input; each logical MFMA =
// 3 MFMAs (Ah*Bh + Al*Bh + Ah*Bl), fp32 accumulate -> ~fp32-precision GEMMs.
//
// Round-7 lesson: __launch_bounds__(512,4) capped regs at 128 -> ~50-reg spill
// -> 2.85 GB scratch writes -> L2 thrash -> 16.8 GB HBM fetch. Round 8:
// 4-wave blocks (256 thr, 32-row tile, 512 blocks = 2 independent blocks/CU),
// __launch_bounds__(256,2) -> 256 unified regs/thread, demand ~150 -> no spill.
// Same per-wave MFMA load as the round-4 anchor; barrier independence across
// blocks provides the latency hiding that round 4 lacked.

typedef _Float16 f16;
typedef _Float16 f16x8 __attribute__((ext_vector_type(8)));
typedef float f32x4 __attribute__((ext_vector_type(4)));

#define LOG2E     1.44269504088896340736f
#define TWOLOG2E  2.88539008177792681472f

#define MFMA3(acc, ah, al, bh, bl)                                        \
  acc = __builtin_amdgcn_mfma_f32_16x16x32_f16(ah, bh, acc, 0, 0, 0);     \
  acc = __builtin_amdgcn_mfma_f32_16x16x32_f16(al, bh, acc, 0, 0, 0);     \
  acc = __builtin_amdgcn_mfma_f32_16x16x32_f16(ah, bl, acc, 0, 0, 0);

// ws layout in f16 elements (hi at [0,90112), lo at [90112,180224)):
//   [0,8192)      W1P  (K=128,N=64)   frag idx ((nt*4+kb)*64+l)*8+j
//   [8192,12288)  W2P  (K=64,N=64)    ((nt*2+kb)*64+l)*8+j
//   [12288,16384) W3P  (K=64,N=64)
//   [16384,90112) W4P  per c: (K=64,N=128 cols 9h+c)  (((c*8+nt)*2+kb)*64+l)*8+j
__global__ void pack_weights(const float* __restrict__ W1, const float* __restrict__ W2,
                             const float* __restrict__ W3, const float* __restrict__ W4,
                             f16* __restrict__ wp)
{
  int t = blockIdx.x * 256 + threadIdx.x;
  if (t >= 90112) return;
  float v;
  if (t < 8192) {
    int j = t & 7, lr = (t >> 3) & 63, kb = (t >> 9) & 3, nt = t >> 11;
    int k = 32*kb + 8*(lr >> 4) + j, n = 16*nt + (lr & 15);
    v = W1[k*64 + n];
  } else if (t < 12288) {
    int u = t - 8192;
    int j = u & 7, lr = (u >> 3) & 63, kb = (u >> 9) & 1, nt = u >> 10;
    int k = 32*kb + 8*(lr >> 4) + j, n = 16*nt + (lr & 15);
    v = W2[k*64 + n];
  } else if (t < 16384) {
    int u = t - 12288;
    int j = u & 7, lr = (u >> 3) & 63, kb = (u >> 9) & 1, nt = u >> 10;
    int k = 32*kb + 8*(lr >> 4) + j, n = 16*nt + (lr & 15);
    v = W3[k*64 + n];
  } else {
    int u = t - 16384;
    int j = u & 7, lr = (u >> 3) & 63, kb = (u >> 9) & 1, nt = (u >> 10) & 7, c = u >> 13;
    int k = 32*kb + 8*(lr >> 4) + j, h = 16*nt + (lr & 15);
    v = W4[k*1152 + 9*h + c];
  }
  f16 hi = (f16)v;
  wp[t] = hi;
  wp[90112 + t] = (f16)(v - (float)hi);
}

__device__ __forceinline__ void tanh_k4(f32x4& K, const f32x4 ac, float b4c, const f32x4 uv) {
#pragma unroll
  for (int r = 0; r < 4; r++) {
    // tanh(pre + b4) = 1 - 2/(exp2((pre+b4)*2log2e)+1)  (inf-safe); b4c pre-scaled
    float tex = __builtin_amdgcn_exp2f(__builtin_fmaf(ac[r], TWOLOG2E, b4c));
    float th  = __builtin_fmaf(__builtin_amdgcn_rcpf(tex + 1.0f), -2.0f, 1.0f);
    K[r] = __builtin_fmaf(th, uv[r], K[r]);
  }
}

// W4 set: channel c, col-tile nt4 (16 cols), kb 0..1, hi+lo: 4 x f16x8 = 16 VGPRs.
#define LOADSET(P, c, nt4) do {                                           \
    int base_ = 2048 + (((c)*8 + (nt4))*2)*64 + l;                        \
    P##h0 = wpv[base_];      P##l0 = wlv[base_];                          \
    P##h1 = wpv[base_ + 64]; P##l1 = wlv[base_ + 64];                     \
  } while (0)

// Compute channel c, this ng's 16 cols, both mi: 4 logical MFMA (x3), tanh, K4.
#define COMPUTE(P, c, colng) do {                                         \
    f32x4 ac0 = zero4, ac1 = zero4;                                       \
    MFMA3(ac0, a4h[0][0], a4l[0][0], P##h0, P##l0);                       \
    MFMA3(ac0, a4h[0][1], a4l[0][1], P##h1, P##l1);                       \
    MFMA3(ac1, a4h[1][0], a4l[1][0], P##h0, P##l0);                       \
    MFMA3(ac1, a4h[1][1], a4l[1][1], P##h1, P##l1);                       \
    float b4c = ((const float*)(smem + B4S))[(c)*128 + (colng)];          \
    f32x4 uv0 = *reinterpret_cast<const f32x4*>(smem + UT + (c)*128 + 16*l4);      \
    f32x4 uv1 = *reinterpret_cast<const f32x4*>(smem + UT + (c)*128 + 64 + 16*l4); \
    tanh_k4(K4[0], ac0, b4c, uv0);                                        \
    tanh_k4(K4[1], ac1, b4c, uv1);                                        \
  } while (0)

// RK4 combine + state write for one ng (16 cols).  K = h*k cumulative trick.
#define RK4EP(ng, colng) do {                                             \
    if (st == 0) { ark[0][ng] = K4[0]; ark[1][ng] = K4[1]; }              \
    else if (st == 3) {                                                   \
      for (int mi = 0; mi < 2; mi++)                                      \
        for (int r = 0; r < 4; r++)                                       \
          z[mi][ng][r] = __builtin_fmaf(ark[mi][ng][r] + K4[mi][r],       \
                                        0.166666666667f, z[mi][ng][r]);   \
    } else {                                                              \
      for (int mi = 0; mi < 2; mi++)                                      \
        for (int r = 0; r < 4; r++)                                       \
          ark[mi][ng][r] = __builtin_fmaf(2.0f, K4[mi][r], ark[mi][ng][r]); \
    }                                                                     \
    const float alpha_ = (st == 2) ? 1.0f : 0.5f;                         \
    for (int mi = 0; mi < 2; mi++)                                        \
      for (int r = 0; r < 4; r++) {                                       \
        float sv = (st == 3) ? z[mi][ng][r]                               \
                             : __builtin_fmaf(alpha_, K4[mi][r], z[mi][ng][r]); \
        int row  = 16*mi + 4*l4 + r;                                      \
        int byte = row*256 + (((colng)*2) ^ ((row & 7) << 4));            \
        f16 hi = (f16)sv;                                                 \
        *reinterpret_cast<f16*>(smem + SH + byte) = hi;                   \
        *reinterpret_cast<f16*>(smem + SL + byte) = (f16)(sv - (float)hi);\
      }                                                                   \
  } while (0)

// LDS map (38528 B), 32-row tile:
//   s_hi[32][128]f16 @0     (8K, rowstride 256B, XOR-swizzled)   s_lo @8192
//   hA_hi[32][64]f16 @16384 (4K, rowstride 128B, swizzled)       hA_lo @20480
//   hB_hi @24576                                                  hB_lo @28672
//   u_t[9][32]f32 @32768 (1152 B)
//   b4s[9][128]f32 @33920 (4608 B)  b4s[c*128+h] = b4[9h+c]*2log2e
// 4 waves (256 thr): G1-3: mh2=w>>1 row-half, nh=w&1 col-half (2 ct each);
//                    G4/state: cols 32w..+31 (2 ng), rows 0..31 (2 mi).
__global__ __launch_bounds__(256, 2) void cde_main(
    const float* __restrict__ x, const f16* __restrict__ wp,
    const float* __restrict__ b1, const float* __restrict__ b2,
    const float* __restrict__ b3, const float* __restrict__ b4,
    const float* __restrict__ Wi, const float* __restrict__ bi,
    const float* __restrict__ Wo, const float* __restrict__ bo,
    float* __restrict__ out)
{
  constexpr int SH = 0, SL = 8192, HAH = 16384, HAL = 20480, HBH = 24576, HBL = 28672;
  constexpr int UT = 32768, B4S = 33920;
  __shared__ __attribute__((aligned(16))) char smem[38528];

  const int tid = threadIdx.x;
  const int w   = tid >> 6;          // wave 0..3
  const int l   = tid & 63;
  const int l15 = l & 15, l4 = l >> 4;
  const int mh2 = w >> 1, nh = w & 1;        // G1-G3 roles
  const int b0  = blockIdx.x << 5;           // batch tile base (32 rows)
  const int xorv = (l15 & 7) << 4;           // A-frag read swizzle (row = ..+l15)

  const f16x8* wpv = reinterpret_cast<const f16x8*>(wp);
  const f16x8* wlv = wpv + 11264;            // lo half (90112/8)

  // per-ct biases for G1-G3 (ct: col-tile nt = 2*nh + ct)
  const float b1v0 = b1[(2*nh+0)*16 + l15], b1v1 = b1[(2*nh+1)*16 + l15];
  const float b2v0 = b2[(2*nh+0)*16 + l15], b2v1 = b2[(2*nh+1)*16 + l15];
  const float b3v0 = b3[(2*nh+0)*16 + l15], b3v1 = b3[(2*nh+1)*16 + l15];
  const float b1x0 = b1v0*LOG2E, b1x1 = b1v1*LOG2E;
  const float b2x0 = b2v0*LOG2E, b2x1 = b2v1*LOG2E;
  const float b3x0 = b3v0*LOG2E, b3x1 = b3v1*LOG2E;

  const f32x4 zero4 = {0.f, 0.f, 0.f, 0.f};

  // ---------------- init LDS: b4s, Wi (@HAH+HAL), bi (@HBH), x0 (@UT) ----------------
  for (int idx = tid; idx < 1152; idx += 256) {
    int h = idx / 9, c = idx - h*9;                     // coalesced read of b4
    ((float*)(smem + B4S))[c*128 + h] = b4[idx] * TWOLOG2E;
  }
  for (int idx = tid; idx < 1152; idx += 256) ((float*)(smem + HAH))[idx] = Wi[idx];
  if (tid < 128) ((float*)(smem + HBH))[tid] = bi[tid];
  for (int idx = tid; idx < 288; idx += 256) {
    int row = idx / 9, c = idx - row*9;                 // coalesced read of x0
    ((float*)(smem + UT))[c*32 + row] = x[(size_t)(b0 + row)*576 + c];
  }
  __syncthreads();

  // RK4 state: rows 16mi+4l4+r, cols 32w+16ng+l15
  f32x4 z[2][2], ark[2][2];
#pragma unroll
  for (int ng = 0; ng < 2; ng++) {
    const int colng = 32*w + 16*ng + l15;
    float wiv[9];
#pragma unroll
    for (int c = 0; c < 9; c++) wiv[c] = ((const float*)(smem + HAH))[c*128 + colng];
    float biv = ((const float*)(smem + HBH))[colng];
#pragma unroll
    for (int mi = 0; mi < 2; mi++) {
      f32x4 zz = {biv, biv, biv, biv};
#pragma unroll
      for (int c = 0; c < 9; c++) {
        f32x4 xv = *reinterpret_cast<const f32x4*>(smem + UT + c*128 + 64*mi + 16*l4);
#pragma unroll
        for (int r = 0; r < 4; r++) zz[r] = __builtin_fmaf(xv[r], wiv[c], zz[r]);
      }
      z[mi][ng] = zz;
#pragma unroll
      for (int r = 0; r < 4; r++) {           // seed s with z0 (split hi/lo)
        int row  = 16*mi + 4*l4 + r;
        int byte = row*256 + ((colng*2) ^ ((row & 7) << 4));
        f16 hi = (f16)zz[r];
        *reinterpret_cast<f16*>(smem + SH + byte) = hi;
        *reinterpret_cast<f16*>(smem + SL + byte) = (f16)(zz[r] - (float)hi);
      }
    }
  }

  // ---------------- time loop ----------------
#pragma unroll 1
  for (int k = 0; k < 63; ++k) {
#pragma unroll 1
    for (int st = 0; st < 4; ++st) {
      __syncthreads();                         // s writes (and prior u_t use) settled

      // W1 fragments, both ct (global/L2, transient 64 regs)
      f16x8 w1h[2][4], w1l[2][4];
#pragma unroll
      for (int ct = 0; ct < 2; ct++)
#pragma unroll
        for (int kb = 0; kb < 4; kb++) {
          int i = ((2*nh+ct)*4 + kb)*64 + l;
          w1h[ct][kb] = wpv[i]; w1l[ct][kb] = wlv[i];
        }

      if (st == 0) {                           // u_t[c][row] = x[k+1]-x[k], coalesced
        for (int idx = tid; idx < 288; idx += 256) {
          int row = idx / 9, c = idx - row*9;
          const float* p = x + (size_t)(b0 + row)*576 + (size_t)k*9 + c;
          ((float*)(smem + UT))[c*32 + row] = p[9] - p[0];
        }
      }

      f16x8 w2h[2][2], w2l[2][2], w3h[2][2], w3l[2][2];
      f16x8 Ah0, Al0, Ah1, Al1, Bh0, Bl0, Bh1, Bl1;   // W4 sets (paired-c)

      // ---- G1: s(32x128) @ W1 -> h1 (hA); rows 16mh2, cols 32nh (2 ct) ----
      {
        f32x4 acc0 = zero4, acc1 = zero4;
#pragma unroll
        for (int kb = 0; kb < 4; kb++) {
          int row = 16*mh2 + l15;
          int off = row*256 + ((16*l4 + 64*kb) ^ xorv);
          f16x8 ah = *reinterpret_cast<const f16x8*>(smem + SH + off);
          f16x8 al = *reinterpret_cast<const f16x8*>(smem + SL + off);
          MFMA3(acc0, ah, al, w1h[0][kb], w1l[0][kb]);
          MFMA3(acc1, ah, al, w1h[1][kb], w1l[1][kb]);
        }
#pragma unroll
        for (int ct = 0; ct < 2; ct++)         // prefetch W2
#pragma unroll
          for (int kb = 0; kb < 2; kb++) {
            int i = 1024 + ((2*nh+ct)*2 + kb)*64 + l;
            w2h[ct][kb] = wpv[i]; w2l[ct][kb] = wlv[i];
          }
#pragma unroll
        for (int ct = 0; ct < 2; ct++) {
          const float bv = ct ? b1v1 : b1v0, bx = ct ? b1x1 : b1x0;
          const f32x4 acc = ct ? acc1 : acc0;
#pragma unroll
          for (int r = 0; r < 4; r++) {
            float pre = acc[r];
            float lin = pre + bv;
            float e   = __builtin_amdgcn_exp2f(__builtin_fmaf(pre, LOG2E, bx)) - 1.0f;
            float res = lin > 0.0f ? lin : e;
            int row  = 16*mh2 + 4*l4 + r;
            int col  = (2*nh+ct)*16 + l15;
            int byte = row*128 + ((col*2) ^ ((row & 7) << 4));
            f16 hi = (f16)res;
            *reinterpret_cast<f16*>(smem + HAH + byte) = hi;
            *reinterpret_cast<f16*>(smem + HAL + byte) = (f16)(res - (float)hi);
          }
        }
      }
      __syncthreads();

      // ---- G2: h1(hA) @ W2 -> h2 (hB) ----
      {
        f32x4 acc0 = zero4, acc1 = zero4;
#pragma unroll
        for (int kb = 0; kb < 2; kb++) {
          int row = 16*mh2 + l15;
          int off = row*128 + ((16*l4 + 64*kb) ^ xorv);
          f16x8 ah = *reinterpret_cast<const f16x8*>(smem + HAH + off);
          f16x8 al = *reinterpret_cast<const f16x8*>(smem + HAL + off);
          MFMA3(acc0, ah, al, w2h[0][kb], w2l[0][kb]);
          MFMA3(acc1, ah, al, w2h[1][kb], w2l[1][kb]);
        }
#pragma unroll
        for (int ct = 0; ct < 2; ct++)         // prefetch W3
#pragma unroll
          for (int kb = 0; kb < 2; kb++) {
            int i = 1536 + ((2*nh+ct)*2 + kb)*64 + l;
            w3h[ct][kb] = wpv[i]; w3l[ct][kb] = wlv[i];
          }
#pragma unroll
        for (int ct = 0; ct < 2; ct++) {
          const float bv = ct ? b2v1 : b2v0, bx = ct ? b2x1 : b2x0;
          const f32x4 acc = ct ? acc1 : acc0;
#pragma unroll
          for (int r = 0; r < 4; r++) {
            float pre = acc[r];
            float lin = pre + bv;
            float e   = __builtin_amdgcn_exp2f(__builtin_fmaf(pre, LOG2E, bx)) - 1.0f;
            float res = lin > 0.0f ? lin : e;
            int row  = 16*mh2 + 4*l4 + r;
            int col  = (2*nh+ct)*16 + l15;
            int byte = row*128 + ((col*2) ^ ((row & 7) << 4));
            f16 hi = (f16)res;
            *reinterpret_cast<f16*>(smem + HBH + byte) = hi;
            *reinterpret_cast<f16*>(smem + HBL + byte) = (f16)(res - (float)hi);
          }
        }
      }
      __syncthreads();

      // ---- G3: h2(hB) @ W3 -> h3 (hA, reuse) ----
      {
        f32x4 acc0 = zero4, acc1 = zero4;
#pragma unroll
        for (int kb = 0; kb < 2; kb++) {
          int row = 16*mh2 + l15;
          int off = row*128 + ((16*l4 + 64*kb) ^ xorv);
          f16x8 ah = *reinterpret_cast<const f16x8*>(smem + HBH + off);
          f16x8 al = *reinterpret_cast<const f16x8*>(smem + HBL + off);
          MFMA3(acc0, ah, al, w3h[0][kb], w3l[0][kb]);
          MFMA3(acc1, ah, al, w3h[1][kb], w3l[1][kb]);
        }
        LOADSET(A, 0, 2*w);                    // prefetch W4 ng=0, c=0,1
        LOADSET(B, 1, 2*w);
#pragma unroll
        for (int ct = 0; ct < 2; ct++) {
          const float bv = ct ? b3v1 : b3v0, bx = ct ? b3x1 : b3x0;
          const f32x4 acc = ct ? acc1 : acc0;
#pragma unroll
          for (int r = 0; r < 4; r++) {
            float pre = acc[r];
            float lin = pre + bv;
            float e   = __builtin_amdgcn_exp2f(__builtin_fmaf(pre, LOG2E, bx)) - 1.0f;
            float res = lin > 0.0f ? lin : e;
            int row  = 16*mh2 + 4*l4 + r;
            int col  = (2*nh+ct)*16 + l15;
            int byte = row*128 + ((col*2) ^ ((row & 7) << 4));
            f16 hi = (f16)res;
            *reinterpret_cast<f16*>(smem + HAH + byte) = hi;
            *reinterpret_cast<f16*>(smem + HAL + byte) = (f16)(res - (float)hi);
          }
        }
      }
      __syncthreads();

      // ---- G4: 9 channel-GEMMs (h3 @ W4_c), tanh, contract with u, RK4 ----
      // cols 32w..+31 as two ng passes (16-reg W4 sets, paired-c prefetch).
      {
        f16x8 a4h[2][2], a4l[2][2];
#pragma unroll
        for (int mi = 0; mi < 2; mi++)
#pragma unroll
          for (int kb = 0; kb < 2; kb++) {
            int row = 16*mi + l15;
            int off = row*128 + ((16*l4 + 64*kb) ^ xorv);
            a4h[mi][kb] = *reinterpret_cast<const f16x8*>(smem + HAH + off);
            a4l[mi][kb] = *reinterpret_cast<const f16x8*>(smem + HAL + off);
          }
        f32x4 K4[2];
        const int col0 = 32*w + l15, col1 = 32*w + 16 + l15;

        // ---- ng = 0 ----
        K4[0] = zero4; K4[1] = zero4;
#pragma unroll 1
        for (int cc = 0; cc < 4; ++cc) {
          COMPUTE(A, 2*cc, col0);
          LOADSET(A, 2*cc + 2, 2*w);           // c = 2,4,6,8
          COMPUTE(B, 2*cc + 1, col0);
          if (cc < 3) LOADSET(B, 2*cc + 3, 2*w);
        }
        COMPUTE(A, 8, col0);
        LOADSET(A, 0, 2*w + 1);                // prefetch ng=1 c=0,1 (hides under RK4EP)
        LOADSET(B, 1, 2*w + 1);
        RK4EP(0, col0);

        // ---- ng = 1 ----
        K4[0] = zero4; K4[1] = zero4;
#pragma unroll 1
        for (int cc = 0; cc < 4; ++cc) {
          COMPUTE(A, 2*cc, col1);
          LOADSET(A, 2*cc + 2, 2*w + 1);
          COMPUTE(B, 2*cc + 1, col1);
          if (cc < 3) LOADSET(B, 2*cc + 3, 2*w + 1);
        }
        COMPUTE(A, 8, col1);
        RK4EP(1, col1);
      }
    }
  }

  // ---------------- out = z @ Wo + bo ----------------
  __syncthreads();
#pragma unroll
  for (int ng = 0; ng < 2; ng++)
#pragma unroll
    for (int mi = 0; mi < 2; mi++)
#pragma unroll
      for (int r = 0; r < 4; r++) {
        int row = 16*mi + 4*l4 + r;
        int col = 32*w + 16*ng + l15;
        ((float*)smem)[row*128 + col] = z[mi][ng][r];  // z32[32][128] @0 (16 KB)
      }
  for (int idx = tid; idx < 1152; idx += 256) ((float*)(smem + HAH))[idx] = Wo[idx];
  __syncthreads();
  for (int idx = tid; idx < 288; idx += 256) {
    int b_ = idx / 9, c = idx - b_*9;
    float acc = bo[c];
#pragma unroll 4
    for (int h = 0; h < 128; h++)
      acc = __builtin_fmaf(((const float*)smem)[b_*128 + h],
                           ((const float*)(smem + HAH))[h*9 + c], acc);
    out[(size_t)(b0 + b_)*9 + c] = acc;
  }
}

extern "C" void kernel_launch(void* const* d_in, const int* in_sizes, int n_in,
                              void* d_out, int out_size, void* d_ws, size_t ws_size,
                              hipStream_t stream)
{
  // setup_inputs order: t, x, W1, b1, W2, b2, W3, b3, W4, b4, Wi, bi, Wo, bo
  const float* x  = (const float*)d_in[1];
  const float* W1 = (const float*)d_in[2];
  const float* b1 = (const float*)d_in[3];
  const float* W2 = (const float*)d_in[4];
  const float* b2 = (const float*)d_in[5];
  const float* W3 = (const float*)d_in[6];
  const float* b3 = (const float*)d_in[7];
  const float* W4 = (const float*)d_in[8];
  const float* b4 = (const float*)d_in[9];
  const float* Wi = (const float*)d_in[10];
  const float* bi = (const float*)d_in[11];
  const float* Wo = (const float*)d_in[12];
  const float* bo = (const float*)d_in[13];
  f16* wp = (f16*)d_ws;                       // 180224 f16 = 360448 B (hi + lo)

  pack_weights<<<352, 256, 0, stream>>>(W1, W2, W3, W4, wp);
  cde_main<<<512, 256, 0, stream>>>(x, wp, b1, b2, b3, b4, Wi, bi, Wo, bo, (float*)d_out);
}

// Round 9
// 3683.000 us; speedup vs baseline: 1.5817x; 1.2594x over previous
//
#include <hip/hip_runtime.h>
#include <cstdint>
#include <cstddef>

// SO3NeuralCDE: B=16384, S=64, C=9, H=128, BN=64.
// RK4 over 63 knot intervals; field = 4-layer MLP (elu,elu,elu,tanh) contracted with dX.
// dt cancels: K_i = f(.) * (x[k+1]-x[k]).  t input unused.
//
// Precision: split fp16 (X = Xh + Xl) on every GEMM input; each logical MFMA =
// 3 MFMAs (Ah*Bh + Al*Bh + Ah*Bl), fp32 accumulate -> ~fp32-precision GEMMs.
//
// Round-8 lesson: per-stage W123 global re-loads missed L2 (FETCH 9.26 GB ~=
// 64KB W123/block-stage) and serialized G1-G3. Round 9: W123-hi in LDS (32KB,
// staged once), W123-lo in persistent VGPRs (64 regs) -> LDS 71.3KB keeps
// 2 independent blocks/CU; W4 remains the only per-stage stream (round-4-proven
// pattern). __launch_bounds__(256,2) -> 256-reg budget, no spill at ~215 peak.

typedef _Float16 f16;
typedef _Float16 f16x8 __attribute__((ext_vector_type(8)));
typedef float f32x4 __attribute__((ext_vector_type(4)));

#define LOG2E     1.44269504088896340736f
#define TWOLOG2E  2.88539008177792681472f

#define MFMA3(acc, ah, al, bh, bl)                                        \
  acc = __builtin_amdgcn_mfma_f32_16x16x32_f16(ah, bh, acc, 0, 0, 0);     \
  acc = __builtin_amdgcn_mfma_f32_16x16x32_f16(al, bh, acc, 0, 0, 0);     \
  acc = __builtin_amdgcn_mfma_f32_16x16x32_f16(ah, bl, acc, 0, 0, 0);

// ws layout in f16 elements (hi at [0,90112), lo at [90112,180224)):
//   [0,8192)      W1P  (K=128,N=64)   frag idx ((nt*4+kb)*64+l)*8+j
//   [8192,12288)  W2P  (K=64,N=64)    ((nt*2+kb)*64+l)*8+j
//   [12288,16384) W3P  (K=64,N=64)
//   [16384,90112) W4P  per c: (K=64,N=128 cols 9h+c)  (((c*8+nt)*2+kb)*64+l)*8+j
__global__ void pack_weights(const float* __restrict__ W1, const float* __restrict__ W2,
                             const float* __restrict__ W3, const float* __restrict__ W4,
                             f16* __restrict__ wp)
{
  int t = blockIdx.x * 256 + threadIdx.x;
  if (t >= 90112) return;
  float v;
  if (t < 8192) {
    int j = t & 7, lr = (t >> 3) & 63, kb = (t >> 9) & 3, nt = t >> 11;
    int k = 32*kb + 8*(lr >> 4) + j, n = 16*nt + (lr & 15);
    v = W1[k*64 + n];
  } else if (t < 12288) {
    int u = t - 8192;
    int j = u & 7, lr = (u >> 3) & 63, kb = (u >> 9) & 1, nt = u >> 10;
    int k = 32*kb + 8*(lr >> 4) + j, n = 16*nt + (lr & 15);
    v = W2[k*64 + n];
  } else if (t < 16384) {
    int u = t - 12288;
    int j = u & 7, lr = (u >> 3) & 63, kb = (u >> 9) & 1, nt = u >> 10;
    int k = 32*kb + 8*(lr >> 4) + j, n = 16*nt + (lr & 15);
    v = W3[k*64 + n];
  } else {
    int u = t - 16384;
    int j = u & 7, lr = (u >> 3) & 63, kb = (u >> 9) & 1, nt = (u >> 10) & 7, c = u >> 13;
    int k = 32*kb + 8*(lr >> 4) + j, h = 16*nt + (lr & 15);
    v = W4[k*1152 + 9*h + c];
  }
  f16 hi = (f16)v;
  wp[t] = hi;
  wp[90112 + t] = (f16)(v - (float)hi);
}

__device__ __forceinline__ void tanh_k4(f32x4& K, const f32x4 ac, float b4c, const f32x4 uv) {
#pragma unroll
  for (int r = 0; r < 4; r++) {
    // tanh(pre + b4) = 1 - 2/(exp2((pre+b4)*2log2e)+1)  (inf-safe); b4c pre-scaled
    float tex = __builtin_amdgcn_exp2f(__builtin_fmaf(ac[r], TWOLOG2E, b4c));
    float th  = __builtin_fmaf(__builtin_amdgcn_rcpf(tex + 1.0f), -2.0f, 1.0f);
    K[r] = __builtin_fmaf(th, uv[r], K[r]);
  }
}

// W4 set: channel c, col-tile nt4 (16 cols), kb 0..1, hi+lo: 4 x f16x8 = 16 VGPRs.
#define LOADSET(P, c, nt4) do {                                           \
    int base_ = 2048 + (((c)*8 + (nt4))*2)*64 + l;                        \
    P##h0 = wpv[base_];      P##l0 = wlv[base_];                          \
    P##h1 = wpv[base_ + 64]; P##l1 = wlv[base_ + 64];                     \
  } while (0)

// Compute channel c, this ng's 16 cols, both mi: 4 logical MFMA (x3), tanh, K4.
#define COMPUTE(P, c, colng) do {                                         \
    f32x4 ac0 = zero4, ac1 = zero4;                                       \
    MFMA3(ac0, a4h[0][0], a4l[0][0], P##h0, P##l0);                       \
    MFMA3(ac0, a4h[0][1], a4l[0][1], P##h1, P##l1);                       \
    MFMA3(ac1, a4h[1][0], a4l[1][0], P##h0, P##l0);                       \
    MFMA3(ac1, a4h[1][1], a4l[1][1], P##h1, P##l1);                       \
    float b4c = ((const float*)(smem + B4S))[(c)*128 + (colng)];          \
    f32x4 uv0 = *reinterpret_cast<const f32x4*>(smem + UT + (c)*128 + 16*l4);      \
    f32x4 uv1 = *reinterpret_cast<const f32x4*>(smem + UT + (c)*128 + 64 + 16*l4); \
    tanh_k4(K4[0], ac0, b4c, uv0);                                        \
    tanh_k4(K4[1], ac1, b4c, uv1);                                        \
  } while (0)

// RK4 combine + state write for one ng (16 cols).  K = h*k cumulative trick.
#define RK4EP(ng, colng) do {                                             \
    if (st == 0) { ark[0][ng] = K4[0]; ark[1][ng] = K4[1]; }              \
    else if (st == 3) {                                                   \
      for (int mi = 0; mi < 2; mi++)                                      \
        for (int r = 0; r < 4; r++)                                       \
          z[mi][ng][r] = __builtin_fmaf(ark[mi][ng][r] + K4[mi][r],       \
                                        0.166666666667f, z[mi][ng][r]);   \
    } else {                                                              \
      for (int mi = 0; mi < 2; mi++)                                      \
        for (int r = 0; r < 4; r++)                                       \
          ark[mi][ng][r] = __builtin_fmaf(2.0f, K4[mi][r], ark[mi][ng][r]); \
    }                                                                     \
    const float alpha_ = (st == 2) ? 1.0f : 0.5f;                         \
    for (int mi = 0; mi < 2; mi++)                                        \
      for (int r = 0; r < 4; r++) {                                       \
        float sv = (st == 3) ? z[mi][ng][r]                               \
                             : __builtin_fmaf(alpha_, K4[mi][r], z[mi][ng][r]); \
        int row  = 16*mi + 4*l4 + r;                                      \
        int byte = row*256 + (((colng)*2) ^ ((row & 7) << 4));            \
        f16 hi = (f16)sv;                                                 \
        *reinterpret_cast<f16*>(smem + SH + byte) = hi;                   \
        *reinterpret_cast<f16*>(smem + SL + byte) = (f16)(sv - (float)hi);\
      }                                                                   \
  } while (0)

// LDS map (71296 B), 32-row tile:
//   s_hi[32][128]f16 @0     (8K, rowstride 256B, XOR-swizzled)   s_lo @8192
//   hA_hi[32][64]f16 @16384 (4K, rowstride 128B, swizzled)       hA_lo @20480
//   hB_hi @24576                                                  hB_lo @28672
//   u_t[9][32]f32 @32768 (1152 B)
//   b4s[9][128]f32 @33920 (4608 B)  b4s[c*128+h] = b4[9h+c]*2log2e
//   W123-hi @38528 (32768 B) = ws f16 elements [0,16384) in frag order
// W123-lo: persistent VGPRs (16 f16x8/thread).  W4: streamed from L2 per stage.
// 4 waves (256 thr): G1-3: mh2=w>>1 row-half, nh=w&1 col-half (2 ct each);
//                    G4/state: cols 32w..+31 (2 ng), rows 0..31 (2 mi).
__global__ __launch_bounds__(256, 2) void cde_main(
    const float* __restrict__ x, const f16* __restrict__ wp,
    const float* __restrict__ b1, const float* __restrict__ b2,
    const float* __restrict__ b3, const float* __restrict__ b4,
    const float* __restrict__ Wi, const float* __restrict__ bi,
    const float* __restrict__ Wo, const float* __restrict__ bo,
    float* __restrict__ out)
{
  constexpr int SH = 0, SL = 8192, HAH = 16384, HAL = 20480, HBH = 24576, HBL = 28672;
  constexpr int UT = 32768, B4S = 33920, WH = 38528;
  __shared__ __attribute__((aligned(16))) char smem[71296];

  const int tid = threadIdx.x;
  const int w   = tid >> 6;          // wave 0..3
  const int l   = tid & 63;
  const int l15 = l & 15, l4 = l >> 4;
  const int mh2 = w >> 1, nh = w & 1;        // G1-G3 roles
  const int b0  = blockIdx.x << 5;           // batch tile base (32 rows)
  const int xorv = (l15 & 7) << 4;           // A-frag read swizzle (row = ..+l15)

  const f16x8* wpv = reinterpret_cast<const f16x8*>(wp);
  const f16x8* wlv = wpv + 11264;            // lo half (90112/8)

  // per-ct biases for G1-G3 (ct: col-tile nt = 2*nh + ct)
  const float b1v0 = b1[(2*nh+0)*16 + l15], b1v1 = b1[(2*nh+1)*16 + l15];
  const float b2v0 = b2[(2*nh+0)*16 + l15], b2v1 = b2[(2*nh+1)*16 + l15];
  const float b3v0 = b3[(2*nh+0)*16 + l15], b3v1 = b3[(2*nh+1)*16 + l15];
  const float b1x0 = b1v0*LOG2E, b1x1 = b1v1*LOG2E;
  const float b2x0 = b2v0*LOG2E, b2x1 = b2v1*LOG2E;
  const float b3x0 = b3v0*LOG2E, b3x1 = b3v1*LOG2E;

  const f32x4 zero4 = {0.f, 0.f, 0.f, 0.f};

  // ---- persistent W123-lo fragments (loaded once, static indices) ----
  f16x8 w1lp[2][4], w2lp[2][2], w3lp[2][2];
#pragma unroll
  for (int ct = 0; ct < 2; ct++) {
#pragma unroll
    for (int kb = 0; kb < 4; kb++) w1lp[ct][kb] = wlv[((2*nh+ct)*4 + kb)*64 + l];
#pragma unroll
    for (int kb = 0; kb < 2; kb++) w2lp[ct][kb] = wlv[1024 + ((2*nh+ct)*2 + kb)*64 + l];
#pragma unroll
    for (int kb = 0; kb < 2; kb++) w3lp[ct][kb] = wlv[1536 + ((2*nh+ct)*2 + kb)*64 + l];
  }

  // ---------------- init LDS: W123-hi, b4s, Wi (@HAH+HAL), bi (@HBH), x0 (@UT) ----------------
  {
    const f32x4* wp4 = reinterpret_cast<const f32x4*>(wp);
    for (int idx = tid; idx < 2048; idx += 256)
      ((f32x4*)(smem + WH))[idx] = wp4[idx];            // ws bytes [0,32768) = W123 hi
  }
  for (int idx = tid; idx < 1152; idx += 256) {
    int h = idx / 9, c = idx - h*9;                     // coalesced read of b4
    ((float*)(smem + B4S))[c*128 + h] = b4[idx] * TWOLOG2E;
  }
  for (int idx = tid; idx < 1152; idx += 256) ((float*)(smem + HAH))[idx] = Wi[idx];
  if (tid < 128) ((float*)(smem + HBH))[tid] = bi[tid];
  for (int idx = tid; idx < 288; idx += 256) {
    int row = idx / 9, c = idx - row*9;                 // coalesced read of x0
    ((float*)(smem + UT))[c*32 + row] = x[(size_t)(b0 + row)*576 + c];
  }
  __syncthreads();

  // RK4 state: rows 16mi+4l4+r, cols 32w+16ng+l15
  f32x4 z[2][2], ark[2][2];
#pragma unroll
  for (int ng = 0; ng < 2; ng++) {
    const int colng = 32*w + 16*ng + l15;
    float wiv[9];
#pragma unroll
    for (int c = 0; c < 9; c++) wiv[c] = ((const float*)(smem + HAH))[c*128 + colng];
    float biv = ((const float*)(smem + HBH))[colng];
#pragma unroll
    for (int mi = 0; mi < 2; mi++) {
      f32x4 zz = {biv, biv, biv, biv};
#pragma unroll
      for (int c = 0; c < 9; c++) {
        f32x4 xv = *reinterpret_cast<const f32x4*>(smem + UT + c*128 + 64*mi + 16*l4);
#pragma unroll
        for (int r = 0; r < 4; r++) zz[r] = __builtin_fmaf(xv[r], wiv[c], zz[r]);
      }
      z[mi][ng] = zz;
#pragma unroll
      for (int r = 0; r < 4; r++) {           // seed s with z0 (split hi/lo)
        int row  = 16*mi + 4*l4 + r;
        int byte = row*256 + ((colng*2) ^ ((row & 7) << 4));
        f16 hi = (f16)zz[r];
        *reinterpret_cast<f16*>(smem + SH + byte) = hi;
        *reinterpret_cast<f16*>(smem + SL + byte) = (f16)(zz[r] - (float)hi);
      }
    }
  }

  // ---------------- time loop ----------------
#pragma unroll 1
  for (int k = 0; k < 63; ++k) {
#pragma unroll 1
    for (int st = 0; st < 4; ++st) {
      __syncthreads();                         // s writes (and prior u_t use) settled

      if (st == 0) {                           // u_t[c][row] = x[k+1]-x[k], coalesced
        for (int idx = tid; idx < 288; idx += 256) {
          int row = idx / 9, c = idx - row*9;
          const float* p = x + (size_t)(b0 + row)*576 + (size_t)k*9 + c;
          ((float*)(smem + UT))[c*32 + row] = p[9] - p[0];
        }
      }

      f16x8 Ah0, Al0, Ah1, Al1, Bh0, Bl0, Bh1, Bl1;   // W4 sets (paired-c)

      // ---- G1: s(32x128) @ W1 -> h1 (hA); rows 16mh2, cols 32nh (2 ct) ----
      {
        f32x4 acc0 = zero4, acc1 = zero4;
#pragma unroll
        for (int kb = 0; kb < 4; kb++) {
          int row = 16*mh2 + l15;
          int off = row*256 + ((16*l4 + 64*kb) ^ xorv);
          f16x8 ah = *reinterpret_cast<const f16x8*>(smem + SH + off);
          f16x8 al = *reinterpret_cast<const f16x8*>(smem + SL + off);
          f16x8 bh0 = *reinterpret_cast<const f16x8*>(smem + WH + (((2*nh+0)*4 + kb)*64 + l)*16);
          f16x8 bh1 = *reinterpret_cast<const f16x8*>(smem + WH + (((2*nh+1)*4 + kb)*64 + l)*16);
          MFMA3(acc0, ah, al, bh0, w1lp[0][kb]);
          MFMA3(acc1, ah, al, bh1, w1lp[1][kb]);
        }
#pragma unroll
        for (int ct = 0; ct < 2; ct++) {
          const float bv = ct ? b1v1 : b1v0, bx = ct ? b1x1 : b1x0;
          const f32x4 acc = ct ? acc1 : acc0;
#pragma unroll
          for (int r = 0; r < 4; r++) {
            float pre = acc[r];
            float lin = pre + bv;
            float e   = __builtin_amdgcn_exp2f(__builtin_fmaf(pre, LOG2E, bx)) - 1.0f;
            float res = lin > 0.0f ? lin : e;
            int row  = 16*mh2 + 4*l4 + r;
            int col  = (2*nh+ct)*16 + l15;
            int byte = row*128 + ((col*2) ^ ((row & 7) << 4));
            f16 hi = (f16)res;
            *reinterpret_cast<f16*>(smem + HAH + byte) = hi;
            *reinterpret_cast<f16*>(smem + HAL + byte) = (f16)(res - (float)hi);
          }
        }
      }
      __syncthreads();

      // ---- G2: h1(hA) @ W2 -> h2 (hB) ----
      {
        f32x4 acc0 = zero4, acc1 = zero4;
#pragma unroll
        for (int kb = 0; kb < 2; kb++) {
          int row = 16*mh2 + l15;
          int off = row*128 + ((16*l4 + 64*kb) ^ xorv);
          f16x8 ah = *reinterpret_cast<const f16x8*>(smem + HAH + off);
          f16x8 al = *reinterpret_cast<const f16x8*>(smem + HAL + off);
          f16x8 bh0 = *reinterpret_cast<const f16x8*>(smem + WH + ((1024 + ((2*nh+0)*2 + kb)*64 + l))*16);
          f16x8 bh1 = *reinterpret_cast<const f16x8*>(smem + WH + ((1024 + ((2*nh+1)*2 + kb)*64 + l))*16);
          MFMA3(acc0, ah, al, bh0, w2lp[0][kb]);
          MFMA3(acc1, ah, al, bh1, w2lp[1][kb]);
        }
#pragma unroll
        for (int ct = 0; ct < 2; ct++) {
          const float bv = ct ? b2v1 : b2v0, bx = ct ? b2x1 : b2x0;
          const f32x4 acc = ct ? acc1 : acc0;
#pragma unroll
          for (int r = 0; r < 4; r++) {
            float pre = acc[r];
            float lin = pre + bv;
            float e   = __builtin_amdgcn_exp2f(__builtin_fmaf(pre, LOG2E, bx)) - 1.0f;
            float res = lin > 0.0f ? lin : e;
            int row  = 16*mh2 + 4*l4 + r;
            int col  = (2*nh+ct)*16 + l15;
            int byte = row*128 + ((col*2) ^ ((row & 7) << 4));
            f16 hi = (f16)res;
            *reinterpret_cast<f16*>(smem + HBH + byte) = hi;
            *reinterpret_cast<f16*>(smem + HBL + byte) = (f16)(res - (float)hi);
          }
        }
      }
      __syncthreads();

      // ---- G3: h2(hB) @ W3 -> h3 (hA, reuse) ----
      {
        f32x4 acc0 = zero4, acc1 = zero4;
#pragma unroll
        for (int kb = 0; kb < 2; kb++) {
          int row = 16*mh2 + l15;
          int off = row*128 + ((16*l4 + 64*kb) ^ xorv);
          f16x8 ah = *reinterpret_cast<const f16x8*>(smem + HBH + off);
          f16x8 al = *reinterpret_cast<const f16x8*>(smem + HBL + off);
          f16x8 bh0 = *reinterpret_cast<const f16x8*>(smem + WH + ((1536 + ((2*nh+0)*2 + kb)*64 + l))*16);
          f16x8 bh1 = *reinterpret_cast<const f16x8*>(smem + WH + ((1536 + ((2*nh+1)*2 + kb)*64 + l))*16);
          MFMA3(acc0, ah, al, bh0, w3lp[0][kb]);
          MFMA3(acc1, ah, al, bh1, w3lp[1][kb]);
        }
        LOADSET(A, 0, 2*w);                    // prefetch W4 ng=0, c=0,1
        LOADSET(B, 1, 2*w);
#pragma unroll
        for (int ct = 0; ct < 2; ct++) {
          const float bv = ct ? b3v1 : b3v0, bx = ct ? b3x1 : b3x0;
          const f32x4 acc = ct ? acc1 : acc0;
#pragma unroll
          for (int r = 0; r < 4; r++) {
            float pre = acc[r];
            float lin = pre + bv;
            float e   = __builtin_amdgcn_exp2f(__builtin_fmaf(pre, LOG2E, bx)) - 1.0f;
            float res = lin > 0.0f ? lin : e;
            int row  = 16*mh2 + 4*l4 + r;
            int col  = (2*nh+ct)*16 + l15;
            int byte = row*128 + ((col*2) ^ ((row & 7) << 4));
            f16 hi = (f16)res;
            *reinterpret_cast<f16*>(smem + HAH + byte) = hi;
            *reinterpret_cast<f16*>(smem + HAL + byte) = (f16)(res - (float)hi);
          }
        }
      }
      __syncthreads();

      // ---- G4: 9 channel-GEMMs (h3 @ W4_c), tanh, contract with u, RK4 ----
      // cols 32w..+31 as two ng passes (16-reg W4 sets, paired-c prefetch).
      {
        f16x8 a4h[2][2], a4l[2][2];
#pragma unroll
        for (int mi = 0; mi < 2; mi++)
#pragma unroll
          for (int kb = 0; kb < 2; kb++) {
            int row = 16*mi + l15;
            int off = row*128 + ((16*l4 + 64*kb) ^ xorv);
            a4h[mi][kb] = *reinterpret_cast<const f16x8*>(smem + HAH + off);
            a4l[mi][kb] = *reinterpret_cast<const f16x8*>(smem + HAL + off);
          }
        f32x4 K4[2];
        const int col0 = 32*w + l15, col1 = 32*w + 16 + l15;

        // ---- ng = 0 ----
        K4[0] = zero4; K4[1] = zero4;
#pragma unroll 1
        for (int cc = 0; cc < 4; ++cc) {
          COMPUTE(A, 2*cc, col0);
          LOADSET(A, 2*cc + 2, 2*w);           // c = 2,4,6,8
          COMPUTE(B, 2*cc + 1, col0);
          if (cc < 3) LOADSET(B, 2*cc + 3, 2*w);
        }
        COMPUTE(A, 8, col0);
        LOADSET(A, 0, 2*w + 1);                // prefetch ng=1 c=0,1 (hides under RK4EP)
        LOADSET(B, 1, 2*w + 1);
        RK4EP(0, col0);

        // ---- ng = 1 ----
        K4[0] = zero4; K4[1] = zero4;
#pragma unroll 1
        for (int cc = 0; cc < 4; ++cc) {
          COMPUTE(A, 2*cc, col1);
          LOADSET(A, 2*cc + 2, 2*w + 1);
          COMPUTE(B, 2*cc + 1, col1);
          if (cc < 3) LOADSET(B, 2*cc + 3, 2*w + 1);
        }
        COMPUTE(A, 8, col1);
        RK4EP(1, col1);
      }
    }
  }

  // ---------------- out = z @ Wo + bo ----------------
  __syncthreads();
#pragma unroll
  for (int ng = 0; ng < 2; ng++)
#pragma unroll
    for (int mi = 0; mi < 2; mi++)
#pragma unroll
      for (int r = 0; r < 4; r++) {
        int row = 16*mi + 4*l4 + r;
        int col = 32*w + 16*ng + l15;
        ((float*)smem)[row*128 + col] = z[mi][ng][r];  // z32[32][128] @0 (16 KB)
      }
  for (int idx = tid; idx < 1152; idx += 256) ((float*)(smem + HAH))[idx] = Wo[idx];
  __syncthreads();
  for (int idx = tid; idx < 288; idx += 256) {
    int b_ = idx / 9, c = idx - b_*9;
    float acc = bo[c];
#pragma unroll 4
    for (int h = 0; h < 128; h++)
      acc = __builtin_fmaf(((const float*)smem)[b_*128 + h],
                           ((const float*)(smem + HAH))[h*9 + c], acc);
    out[(size_t)(b0 + b_)*9 + c] = acc;
  }
}

extern "C" void kernel_launch(void* const* d_in, const int* in_sizes, int n_in,
                              void* d_out, int out_size, void* d_ws, size_t ws_size,
                              hipStream_t stream)
{
  // setup_inputs order: t, x, W1, b1, W2, b2, W3, b3, W4, b4, Wi, bi, Wo, bo
  const float* x  = (const float*)d_in[1];
  const float* W1 = (const float*)d_in[2];
  const float* b1 = (const float*)d_in[3];
  const float* W2 = (const float*)d_in[4];
  const float* b2 = (const float*)d_in[5];
  const float* W3 = (const float*)d_in[6];
  const float* b3 = (const float*)d_in[7];
  const float* W4 = (const float*)d_in[8];
  const float* b4 = (const float*)d_in[9];
  const float* Wi = (const float*)d_in[10];
  const float* bi = (const float*)d_in[11];
  const float* Wo = (const float*)d_in[12];
  const float* bo = (const float*)d_in[13];
  f16* wp = (f16*)d_ws;                       // 180224 f16 = 360448 B (hi + lo)

  pack_weights<<<352, 256, 0, stream>>>(W1, W2, W3, W4, wp);
  cde_main<<<512, 256, 0, stream>>>(x, wp, b1, b2, b3, b4, Wi, bi, Wo, bo, (float*)d_out);
}

// Round 10
// 2736.767 us; speedup vs baseline: 2.1285x; 1.3457x over previous
//
#include <hip/hip_runtime.h>
#include <cstdint>
#include <cstddef>

// SO3NeuralCDE: B=16384, S=64, C=9, H=128, BN=64.
// RK4 over 63 knot intervals; field = 4-layer MLP (elu,elu,elu,tanh) contracted with dX.
// dt cancels: K_i = f(.) * (x[k+1]-x[k]).  t input unused.
//
// Precision: split fp16 (X = Xh + Xl) on every GEMM input; each logical MFMA =
// 3 MFMAs (Ah*Bh + Al*Bh + Ah*Bl), fp32 accumulate -> ~fp32-precision GEMMs.
//
// Rounds 5-9 post-mortem: every occupancy-raising restructure lost to the
// {LDS, VGPR, L2-stream} trilemma (lockstep barriers / W123 stream misses /
// reg caps -> spill / 2x W4 coverage -> L2 misses). This is the round-4
// optimum config (256 blocks x 512 thr, 64-row tile, 1 block/CU, W123 hi+lo
// in LDS, W4 streamed at 1x coverage) + two proven-safe deltas:
//   (a) u_t staged under the st==0 stage barrier (-63 barriers),
//   (b) coalesced u_t global reads.

typedef _Float16 f16;
typedef _Float16 f16x8 __attribute__((ext_vector_type(8)));
typedef float f32x4 __attribute__((ext_vector_type(4)));

#define LOG2E     1.44269504088896340736f
#define TWOLOG2E  2.88539008177792681472f

#define MFMA3(acc, ah, al, bh, bl)                                        \
  acc = __builtin_amdgcn_mfma_f32_16x16x32_f16(ah, bh, acc, 0, 0, 0);     \
  acc = __builtin_amdgcn_mfma_f32_16x16x32_f16(al, bh, acc, 0, 0, 0);     \
  acc = __builtin_amdgcn_mfma_f32_16x16x32_f16(ah, bl, acc, 0, 0, 0);

// ws layout in f16 elements (hi at [0,90112), lo at [90112,180224)):
//   [0,8192)      W1P  (K=128,N=64)   frag idx ((nt*4+kb)*64+l)*8+j
//   [8192,12288)  W2P  (K=64,N=64)    ((nt*2+kb)*64+l)*8+j
//   [12288,16384) W3P  (K=64,N=64)
//   [16384,90112) W4P  per c: (K=64,N=128 cols 9h+c)  (((c*8+nt)*2+kb)*64+l)*8+j
__global__ void pack_weights(const float* __restrict__ W1, const float* __restrict__ W2,
                             const float* __restrict__ W3, const float* __restrict__ W4,
                             f16* __restrict__ wp)
{
  int t = blockIdx.x * 256 + threadIdx.x;
  if (t >= 90112) return;
  float v;
  if (t < 8192) {
    int j = t & 7, lr = (t >> 3) & 63, kb = (t >> 9) & 3, nt = t >> 11;
    int k = 32*kb + 8*(lr >> 4) + j, n = 16*nt + (lr & 15);
    v = W1[k*64 + n];
  } else if (t < 12288) {
    int u = t - 8192;
    int j = u & 7, lr = (u >> 3) & 63, kb = (u >> 9) & 1, nt = u >> 10;
    int k = 32*kb + 8*(lr >> 4) + j, n = 16*nt + (lr & 15);
    v = W2[k*64 + n];
  } else if (t < 16384) {
    int u = t - 12288;
    int j = u & 7, lr = (u >> 3) & 63, kb = (u >> 9) & 1, nt = u >> 10;
    int k = 32*kb + 8*(lr >> 4) + j, n = 16*nt + (lr & 15);
    v = W3[k*64 + n];
  } else {
    int u = t - 16384;
    int j = u & 7, lr = (u >> 3) & 63, kb = (u >> 9) & 1, nt = (u >> 10) & 7, c = u >> 13;
    int k = 32*kb + 8*(lr >> 4) + j, h = 16*nt + (lr & 15);
    v = W4[k*1152 + 9*h + c];
  }
  f16 hi = (f16)v;
  wp[t] = hi;
  wp[90112 + t] = (f16)(v - (float)hi);
}

// LDS map (137984 B):
//   s_hi[64][128]f16 @0      (16K, rowstride 256B, XOR-swizzled)   s_lo @16384
//   hA_hi[64][64]f16 @32768  (8K,  rowstride 128B, swizzled)       hA_lo @40960
//   hB_hi @49152                                                    hB_lo @57344
//   u_t[9][64]f32 @65536 (2304 B)
//   W123 hi @67840 (32768 B, packed frag order = ws elements [0,16384))
//   W123 lo @100608 (32768 B)
//   b4s[9][128]f32 @133376 (4608 B)  b4s[c*128+h] = b4[9h+c]*2log2e
// G1: s->hA (h1); G2: hA->hB (h2); G3: hB->hA (h3); G4: hA.
// Final epilogue reuses [0,32768) as z32[64][128]f32 and @49152 for Wo.
__global__ __launch_bounds__(512, 2) void cde_main(
    const float* __restrict__ x, const f16* __restrict__ wp,
    const float* __restrict__ b1, const float* __restrict__ b2,
    const float* __restrict__ b3, const float* __restrict__ b4,
    const float* __restrict__ Wi, const float* __restrict__ bi,
    const float* __restrict__ Wo, const float* __restrict__ bo,
    float* __restrict__ out)
{
  constexpr int SH = 0, SL = 16384, HAH = 32768, HAL = 40960, HBH = 49152, HBL = 57344;
  constexpr int UT = 65536, WH = 67840, WL = 100608, B4S = 133376;
  __shared__ __attribute__((aligned(16))) char smem[137984];

  const int tid = threadIdx.x;
  const int w   = tid >> 6;          // wave 0..7
  const int l   = tid & 63;
  const int l15 = l & 15, l4 = l >> 4;
  const int mh  = w >> 2, nq = w & 3;        // roles for G1-G3 (M-half, N-quarter)
  const int b0  = blockIdx.x << 6;           // batch tile base
  const int colG4 = (w << 4) + l15;          // this wave's h-column in G4/state
  const int xorv  = (l15 & 7) << 4;          // A-frag read swizzle (row = ..+l15)

  const f16x8* wpv = reinterpret_cast<const f16x8*>(wp);
  const f16x8* wlv = wpv + 11264;            // lo half (90112/8)

  const float b1v = b1[(nq<<4) + l15], b2v = b2[(nq<<4) + l15], b3v = b3[(nq<<4) + l15];
  const float b1x = b1v * LOG2E, b2x = b2v * LOG2E, b3x = b3v * LOG2E;

  const f32x4 zero4 = {0.f, 0.f, 0.f, 0.f};

  // ---------------- stage W1-3 frags (hi+lo) + b4s into LDS; init z0 inputs ----------------
  {
    const f32x4* wp4 = reinterpret_cast<const f32x4*>(wp);
    for (int idx = tid; idx < 2048; idx += 512) {
      ((f32x4*)(smem + WH))[idx] = wp4[idx];            // ws bytes [0,32768)
      ((f32x4*)(smem + WL))[idx] = wp4[11264 + idx];    // ws bytes [180224,212992)
    }
  }
  for (int idx = tid; idx < 1152; idx += 512) {
    int h = idx / 9, c = idx - h*9;                     // coalesced read of b4
    ((float*)(smem + B4S))[c*128 + h] = b4[idx] * TWOLOG2E;
  }
  for (int idx = tid; idx < 1152; idx += 512) ((float*)(smem + HAH))[idx] = Wi[idx];
  for (int idx = tid; idx <  128; idx += 512) ((float*)(smem + HBH))[idx] = bi[idx];
  for (int idx = tid; idx <  576; idx += 512) {
    int row = idx / 9, c = idx - row*9;                 // coalesced read of x0
    ((float*)(smem + UT))[c*64 + row] = x[(size_t)(b0 + row)*576 + c];
  }
  __syncthreads();

  f32x4 z[4], ark[4];
  {
    float wiv[9];
#pragma unroll
    for (int c = 0; c < 9; c++) wiv[c] = ((const float*)(smem + HAH))[c*128 + colG4];
    float biv = ((const float*)(smem + HBH))[colG4];
#pragma unroll
    for (int mi = 0; mi < 4; mi++) {
      f32x4 zz = {biv, biv, biv, biv};
#pragma unroll
      for (int c = 0; c < 9; c++) {
        f32x4 xv = *reinterpret_cast<const f32x4*>(smem + UT + c*256 + mi*64 + 16*l4);
#pragma unroll
        for (int r = 0; r < 4; r++) zz[r] = __builtin_fmaf(xv[r], wiv[c], zz[r]);
      }
      z[mi] = zz;
#pragma unroll
      for (int r = 0; r < 4; r++) {           // seed s with z0 (split hi/lo)
        int row  = 16*mi + 4*l4 + r;
        int byte = row*256 + ((colG4*2) ^ ((row & 7) << 4));
        f16 hi = (f16)zz[r];
        *reinterpret_cast<f16*>(smem + SH + byte) = hi;
        *reinterpret_cast<f16*>(smem + SL + byte) = (f16)(zz[r] - (float)hi);
      }
    }
  }

  // ---------------- time loop ----------------
#pragma unroll 1
  for (int k = 0; k < 63; ++k) {
#pragma unroll 1
    for (int st = 0; st < 4; ++st) {
      __syncthreads();                         // s (and prior u_t use) settled

      if (st == 0) {                           // u_t[c][row] = x[k+1]-x[k], coalesced
        for (int idx = tid; idx < 576; idx += 512) {
          int row = idx / 9, c = idx - row*9;
          const float* p = x + (size_t)(b0 + row)*576 + (size_t)k*9 + c;
          ((float*)(smem + UT))[c*64 + row] = p[9] - p[0];
        }
      }

      // ---- G1: s(64x128) @ W1 -> h1 (hA) ----
      {
        f32x4 acc[2];
        acc[0] = zero4; acc[1] = zero4;
#pragma unroll
        for (int kb = 0; kb < 4; kb++) {
          int wb = ((nq*4 + kb)*64 + l)*16;
          f16x8 bh = *reinterpret_cast<const f16x8*>(smem + WH + wb);
          f16x8 bl = *reinterpret_cast<const f16x8*>(smem + WL + wb);
#pragma unroll
          for (int mi = 0; mi < 2; mi++) {
            int row = 32*mh + 16*mi + l15;
            int off = row*256 + ((16*l4 + 64*kb) ^ xorv);
            f16x8 ah = *reinterpret_cast<const f16x8*>(smem + SH + off);
            f16x8 al = *reinterpret_cast<const f16x8*>(smem + SL + off);
            MFMA3(acc[mi], ah, al, bh, bl);
          }
        }
#pragma unroll
        for (int mi = 0; mi < 2; mi++)
#pragma unroll
          for (int r = 0; r < 4; r++) {
            float pre = acc[mi][r];
            float lin = pre + b1v;
            float e   = __builtin_amdgcn_exp2f(__builtin_fmaf(pre, LOG2E, b1x)) - 1.0f;
            float res = lin > 0.0f ? lin : e;
            int row  = 32*mh + 16*mi + 4*l4 + r;
            int byte = row*128 + ((((nq<<4) + l15)*2) ^ ((row & 7) << 4));
            f16 hi = (f16)res;
            *reinterpret_cast<f16*>(smem + HAH + byte) = hi;
            *reinterpret_cast<f16*>(smem + HAL + byte) = (f16)(res - (float)hi);
          }
      }
      __syncthreads();

      // ---- G2: h1(hA) @ W2 -> h2 (hB) ----
      {
        f32x4 acc[2];
        acc[0] = zero4; acc[1] = zero4;
#pragma unroll
        for (int kb = 0; kb < 2; kb++) {
          int wb = (1024 + (nq*2 + kb)*64 + l)*16;
          f16x8 bh = *reinterpret_cast<const f16x8*>(smem + WH + wb);
          f16x8 bl = *reinterpret_cast<const f16x8*>(smem + WL + wb);
#pragma unroll
          for (int mi = 0; mi < 2; mi++) {
            int row = 32*mh + 16*mi + l15;
            int off = row*128 + ((16*l4 + 64*kb) ^ xorv);
            f16x8 ah = *reinterpret_cast<const f16x8*>(smem + HAH + off);
            f16x8 al = *reinterpret_cast<const f16x8*>(smem + HAL + off);
            MFMA3(acc[mi], ah, al, bh, bl);
          }
        }
#pragma unroll
        for (int mi = 0; mi < 2; mi++)
#pragma unroll
          for (int r = 0; r < 4; r++) {
            float pre = acc[mi][r];
            float lin = pre + b2v;
            float e   = __builtin_amdgcn_exp2f(__builtin_fmaf(pre, LOG2E, b2x)) - 1.0f;
            float res = lin > 0.0f ? lin : e;
            int row  = 32*mh + 16*mi + 4*l4 + r;
            int byte = row*128 + ((((nq<<4) + l15)*2) ^ ((row & 7) << 4));
            f16 hi = (f16)res;
            *reinterpret_cast<f16*>(smem + HBH + byte) = hi;
            *reinterpret_cast<f16*>(smem + HBL + byte) = (f16)(res - (float)hi);
          }
      }
      __syncthreads();

      // ---- G3: h2(hB) @ W3 -> h3 (hA, reuse) ----
      {
        f32x4 acc[2];
        acc[0] = zero4; acc[1] = zero4;
#pragma unroll
        for (int kb = 0; kb < 2; kb++) {
          int wb = (1536 + (nq*2 + kb)*64 + l)*16;
          f16x8 bh = *reinterpret_cast<const f16x8*>(smem + WH + wb);
          f16x8 bl = *reinterpret_cast<const f16x8*>(smem + WL + wb);
#pragma unroll
          for (int mi = 0; mi < 2; mi++) {
            int row = 32*mh + 16*mi + l15;
            int off = row*128 + ((16*l4 + 64*kb) ^ xorv);
            f16x8 ah = *reinterpret_cast<const f16x8*>(smem + HBH + off);
            f16x8 al = *reinterpret_cast<const f16x8*>(smem + HBL + off);
            MFMA3(acc[mi], ah, al, bh, bl);
          }
        }
#pragma unroll
        for (int mi = 0; mi < 2; mi++)
#pragma unroll
          for (int r = 0; r < 4; r++) {
            float pre = acc[mi][r];
            float lin = pre + b3v;
            float e   = __builtin_amdgcn_exp2f(__builtin_fmaf(pre, LOG2E, b3x)) - 1.0f;
            float res = lin > 0.0f ? lin : e;
            int row  = 32*mh + 16*mi + 4*l4 + r;
            int byte = row*128 + ((((nq<<4) + l15)*2) ^ ((row & 7) << 4));
            f16 hi = (f16)res;
            *reinterpret_cast<f16*>(smem + HAH + byte) = hi;
            *reinterpret_cast<f16*>(smem + HAL + byte) = (f16)(res - (float)hi);
          }
      }
      __syncthreads();

      // ---- G4: 9 channel-GEMMs (h3 @ W4_c), tanh, contract with u, RK4 ----
      // ROLLED c-loop + 1-deep W4-fragment prefetch (32 VGPRs in flight).
      {
        f16x8 a4h[4][2], a4l[4][2];
#pragma unroll
        for (int mi = 0; mi < 4; mi++)
#pragma unroll
          for (int kb = 0; kb < 2; kb++) {
            int row = 16*mi + l15;
            int off = row*128 + ((16*l4 + 64*kb) ^ xorv);
            a4h[mi][kb] = *reinterpret_cast<const f16x8*>(smem + HAH + off);
            a4l[mi][kb] = *reinterpret_cast<const f16x8*>(smem + HAL + off);
          }
        f32x4 K4[4];
#pragma unroll
        for (int mi = 0; mi < 4; mi++) K4[mi] = zero4;

        int ib = 2048 + (w*2)*64 + l;                  // c = 0 fragments
        f16x8 cbh0 = wpv[ib], cbl0 = wlv[ib], cbh1 = wpv[ib + 64], cbl1 = wlv[ib + 64];
#pragma unroll 1
        for (int c = 0; c < 9; c++) {
          f16x8 bh0 = cbh0, bl0 = cbl0, bh1 = cbh1, bl1 = cbl1;
          if (c < 8) {                                 // prefetch c+1 (wave-uniform branch)
            int jb = 2048 + (((c + 1)*8 + w)*2)*64 + l;
            cbh0 = wpv[jb]; cbl0 = wlv[jb]; cbh1 = wpv[jb + 64]; cbl1 = wlv[jb + 64];
          }
          f32x4 ac[4];
#pragma unroll
          for (int mi = 0; mi < 4; mi++) {
            ac[mi] = zero4;
            MFMA3(ac[mi], a4h[mi][0], a4l[mi][0], bh0, bl0);
            MFMA3(ac[mi], a4h[mi][1], a4l[mi][1], bh1, bl1);
          }
          float b4c = ((const float*)(smem + B4S))[c*128 + colG4];
#pragma unroll
          for (int mi = 0; mi < 4; mi++) {
            f32x4 uv = *reinterpret_cast<const f32x4*>(smem + UT + c*256 + mi*64 + 16*l4);
#pragma unroll
            for (int r = 0; r < 4; r++) {
              // tanh(pre + b4) = 1 - 2/(exp2((pre+b4)*2log2e)+1)  (inf-safe)
              float tex = __builtin_amdgcn_exp2f(__builtin_fmaf(ac[mi][r], TWOLOG2E, b4c));
              float th  = __builtin_fmaf(__builtin_amdgcn_rcpf(tex + 1.0f), -2.0f, 1.0f);
              K4[mi][r] = __builtin_fmaf(th, uv[r], K4[mi][r]);
            }
          }
        }
        // RK4 combine (K = h*k): ark=K1+2K2+2K3; z += (ark+K4)/6
        if (st == 0) {
#pragma unroll
          for (int mi = 0; mi < 4; mi++) ark[mi] = K4[mi];
        } else if (st == 3) {
#pragma unroll
          for (int mi = 0; mi < 4; mi++)
#pragma unroll
            for (int r = 0; r < 4; r++)
              z[mi][r] = __builtin_fmaf(ark[mi][r] + K4[mi][r], 0.166666666667f, z[mi][r]);
        } else {
#pragma unroll
          for (int mi = 0; mi < 4; mi++)
#pragma unroll
            for (int r = 0; r < 4; r++)
              ark[mi][r] = __builtin_fmaf(2.0f, K4[mi][r], ark[mi][r]);
        }
        const float alpha = (st == 2) ? 1.0f : 0.5f;
#pragma unroll
        for (int mi = 0; mi < 4; mi++)
#pragma unroll
          for (int r = 0; r < 4; r++) {
            float sv = (st == 3) ? z[mi][r] : __builtin_fmaf(alpha, K4[mi][r], z[mi][r]);
            int row  = 16*mi + 4*l4 + r;
            int byte = row*256 + ((colG4*2) ^ ((row & 7) << 4));
            f16 hi = (f16)sv;
            *reinterpret_cast<f16*>(smem + SH + byte) = hi;
            *reinterpret_cast<f16*>(smem + SL + byte) = (f16)(sv - (float)hi);
          }
      }
    }
  }

  // ---------------- out = z @ Wo + bo ----------------
  __syncthreads();
#pragma unroll
  for (int mi = 0; mi < 4; mi++)
#pragma unroll
    for (int r = 0; r < 4; r++) {
      int row = 16*mi + 4*l4 + r;
      ((float*)smem)[row*128 + colG4] = z[mi][r];        // z32[64][128] @0
    }
  for (int idx = tid; idx < 1152; idx += 512) ((float*)(smem + HBH))[idx] = Wo[idx];
  __syncthreads();
  for (int idx = tid; idx < 576; idx += 512) {
    int b_ = idx / 9, c = idx - b_*9;
    float acc = bo[c];
#pragma unroll 4
    for (int h = 0; h < 128; h++)
      acc = __builtin_fmaf(((const float*)smem)[b_*128 + h],
                           ((const float*)(smem + HBH))[h*9 + c], acc);
    out[(size_t)(b0 + b_)*9 + c] = acc;
  }
}

extern "C" void kernel_launch(void* const* d_in, const int* in_sizes, int n_in,
                              void* d_out, int out_size, void* d_ws, size_t ws_size,
                              hipStream_t stream)
{
  // setup_inputs order: t, x, W1, b1, W2, b2, W3, b3, W4, b4, Wi, bi, Wo, bo
  const float* x  = (const float*)d_in[1];
  const float* W1 = (const float*)d_in[2];
  const float* b1 = (const float*)d_in[3];
  const float* W2 = (const float*)d_in[4];
  const float* b2 = (const float*)d_in[5];
  const float* W3 = (const float*)d_in[6];
  const float* b3 = (const float*)d_in[7];
  const float* W4 = (const float*)d_in[8];
  const float* b4 = (const float*)d_in[9];
  const float* Wi = (const float*)d_in[10];
  const float* bi = (const float*)d_in[11];
  const float* Wo = (const float*)d_in[12];
  const float* bo = (const float*)d_in[13];
  f16* wp = (f16*)d_ws;                       // 180224 f16 = 360448 B (hi + lo)

  pack_weights<<<352, 256, 0, stream>>>(W1, W2, W3, W4, wp);
  cde_main<<<256, 512, 0, stream>>>(x, wp, b1, b2, b3, b4, Wi, bi, Wo, bo, (float*)d_out);
}